// Round 13
// baseline (260.514 us; speedup 1.0000x reference)
//
#include <hip/hip_runtime.h>
#include <hip/hip_bf16.h>

// HyConv round 13: build payload via fire-and-forget atomicOr (4 B TCC traffic per
// entry — r2 evidence: atomics cost exactly 4 B WRITE, scattered stores cost ~50 B).
// Packs two u16 entries per u32 word; memory image identical to the u16 lists the
// r11 phases read, so phases are untouched. Single copy, CAP=64, fused build||gemm.
// memset(ctr+src 10.56MB) -> build_gemm -> phase1_pull -> phase2_pull

#define BB 4
#define NN 10000
#define MM 10000
#define EE 160000
#define CC 128
#define BM (BB * MM)   // 40000 hyperedge buckets
#define BN (BB * NN)   // 40000 node buckets
#define CAP 64         // bucket capacity (validated exact vs CSR in rounds 3/4)

typedef unsigned short u16;
typedef unsigned int u32;
using bf16 = __hip_bfloat16;

// ---------------- fused: gemm (bi%3==0) || build (bi%3!=0) ----------------
// grid = 3750: 1250 gemm blocks (32 rows each), 2500 build blocks (640k edges).
__global__ __launch_bounds__(256) void build_gemm_k(const int* __restrict__ H,
                                                    int* __restrict__ ctr,
                                                    u32* __restrict__ srcA,
                                                    u32* __restrict__ srcB,
                                                    const float* __restrict__ x,
                                                    const float* __restrict__ theta,
                                                    u16* __restrict__ xt) {
    __shared__ float sTh[64 * 128];  // 32 KB
    __shared__ float sX[32 * 128];   // 16 KB
    const int bi = blockIdx.x;

    if (bi % 3 != 0) {
        // ---- build: one thread per edge; payload appended via atomicOr ----
        const int j = bi - bi / 3 - 1;               // 0..2499 among build blocks
        const int g = j * 256 + threadIdx.x;         // 0..639,999
        if (g >= BB * EE) return;
        const int b = g / EE, e = g - b * EE;
        const int nd = H[b * 2 * EE + e];
        const int he = H[b * 2 * EE + EE + e];
        const int bktA = b * MM + he;
        const int s = atomicAdd(&ctr[bktA], 1);
        if (s < CAP)
            atomicOr(&srcA[bktA * (CAP / 2) + (s >> 1)], (u32)nd << ((s & 1) * 16));
        const int bktB = b * NN + nd;
        const int q = atomicAdd(&ctr[BM + bktB], 1);
        if (q < CAP)
            atomicOr(&srcB[bktB * (CAP / 2) + (q >> 1)], (u32)he << ((q & 1) * 16));
        return;
    }

    // ---- gemm: 32 rows x 128 cols per block; thread = 8 rows x 2 cols ----
    const int tid = threadIdx.x;
    const int row0 = (bi / 3) * 32;  // rows 0..39968
    {
        const float4* src = (const float4*)&x[row0 * 128];
        float4* dst = (float4*)sX;
#pragma unroll
        for (int i = 0; i < 4; ++i) dst[tid + 256 * i] = src[tid + 256 * i];
    }
    const int cg2 = (tid & 63) * 2;
    const int rg = tid >> 6;
    float ax[8], ay[8];
#pragma unroll
    for (int r = 0; r < 8; ++r) { ax[r] = 0.f; ay[r] = 0.f; }

    for (int half = 0; half < 2; ++half) {
        __syncthreads();
        {
            const float4* src = (const float4*)&theta[half * 64 * 128];
            float4* dst = (float4*)sTh;
#pragma unroll
            for (int i = 0; i < 8; ++i) dst[tid + 256 * i] = src[tid + 256 * i];
        }
        __syncthreads();
#pragma unroll
        for (int k4 = 0; k4 < 16; ++k4) {
            const int kk = 4 * k4;
            const float2 t0 = *(const float2*)&sTh[(kk + 0) * 128 + cg2];
            const float2 t1 = *(const float2*)&sTh[(kk + 1) * 128 + cg2];
            const float2 t2 = *(const float2*)&sTh[(kk + 2) * 128 + cg2];
            const float2 t3 = *(const float2*)&sTh[(kk + 3) * 128 + cg2];
#pragma unroll
            for (int r = 0; r < 8; ++r) {
                const float4 xv =
                    *(const float4*)&sX[(rg * 8 + r) * 128 + half * 64 + kk];
                ax[r] = fmaf(xv.x, t0.x, ax[r]); ay[r] = fmaf(xv.x, t0.y, ay[r]);
                ax[r] = fmaf(xv.y, t1.x, ax[r]); ay[r] = fmaf(xv.y, t1.y, ay[r]);
                ax[r] = fmaf(xv.z, t2.x, ax[r]); ay[r] = fmaf(xv.z, t2.y, ay[r]);
                ax[r] = fmaf(xv.w, t3.x, ax[r]); ay[r] = fmaf(xv.w, t3.y, ay[r]);
            }
        }
    }
#pragma unroll
    for (int r = 0; r < 8; ++r) {
        bf16 hx = __float2bfloat16(ax[r]);
        bf16 hy = __float2bfloat16(ay[r]);
        const unsigned pk = (unsigned)*(u16*)&hx | ((unsigned)*(u16*)&hy << 16);
        *(unsigned*)(xt + (size_t)(row0 + rg * 8 + r) * CC + cg2) = pk;
    }
}

__device__ __forceinline__ float bflo(unsigned r) { return __uint_as_float(r << 16); }
__device__ __forceinline__ float bfhi(unsigned r) {
    return __uint_as_float(r & 0xffff0000u);
}

// ---------------- shared gather: pair-split half-wave, clamped chunks --------------
// lane = 32*half + cl; entry (2k+half) of a chunk lives in packed word k, half selects
// lo/hi. Each gather instr covers TWO rows (8 B = 4 channels per lane).
__device__ __forceinline__ float4 bucket_mean_ps(const u16* __restrict__ base,
                                                 const u16* __restrict__ lst, int cnt,
                                                 int half) {
    float4 acc = {0.f, 0.f, 0.f, 0.f};
    const int nch = (cnt + 15) >> 4;  // 16-entry chunks
    const int hsh = half * 16;
    for (int c = 0; c < nch; ++c) {
        const int i0 = c * 16;
        const uint4 wa = *(const uint4*)&lst[i0];      // entries i0..i0+7
        const uint4 wb = *(const uint4*)&lst[i0 + 8];  // entries i0+8..i0+15
        const unsigned wrd[8] = {wa.x, wa.y, wa.z, wa.w, wb.x, wb.y, wb.z, wb.w};
#pragma unroll
        for (int k = 0; k < 8; ++k) {
            const int e = i0 + 2 * k + half;
            const int idx = (int)((wrd[k] >> hsh) & 0x3fffu);  // mask keeps stale in-ws
            const uint2 raw = *(const uint2*)&base[(size_t)idx * CC];  // unconditional
            if (e < cnt) {  // predicated accumulate only
                acc.x += bflo(raw.x); acc.y += bfhi(raw.x);
                acc.z += bflo(raw.y); acc.w += bfhi(raw.y);
            }
        }
    }
    // cross-half combine: lanes 0..31 end with full sums
    acc.x += __shfl_down(acc.x, 32);
    acc.y += __shfl_down(acc.y, 32);
    acc.z += __shfl_down(acc.z, 32);
    acc.w += __shfl_down(acc.w, 32);
    return acc;
}

// ---------------- phase1: x_edge[bkt] = mean over incident nodes of xt --------------
__global__ __launch_bounds__(256) void phase1_pull(const u16* __restrict__ xt,
                                                   const int* __restrict__ ctr,
                                                   const u16* __restrict__ srcA,
                                                   u16* __restrict__ x_edge) {
    const int wid = (blockIdx.x * 256 + threadIdx.x) >> 6;  // bucket = b*MM+he
    const int lane = threadIdx.x & 63;
    const int half = lane >> 5, cl = lane & 31;
    int cnt = ctr[wid];
    cnt = cnt > CAP ? CAP : cnt;
    const u16* lst = srcA + (size_t)wid * CAP;
    const u16* base = xt + (size_t)(wid / MM) * NN * CC + cl * 4;
    const float4 acc = bucket_mean_ps(base, lst, cnt, half);
    if (lane < 32) {
        const float w = cnt ? 1.0f / (float)cnt : 0.f;
        bf16 h0 = __float2bfloat16(acc.x * w);
        bf16 h1 = __float2bfloat16(acc.y * w);
        bf16 h2 = __float2bfloat16(acc.z * w);
        bf16 h3 = __float2bfloat16(acc.w * w);
        uint2 pk;
        pk.x = (unsigned)*(u16*)&h0 | ((unsigned)*(u16*)&h1 << 16);
        pk.y = (unsigned)*(u16*)&h2 | ((unsigned)*(u16*)&h3 << 16);
        *(uint2*)&x_edge[(size_t)wid * CC + cl * 4] = pk;
    }
}

// ---------------- phase2: out[bkt] = mean over incident hyperedges + bias -----------
__global__ __launch_bounds__(256) void phase2_pull(const u16* __restrict__ x_edge,
                                                   const int* __restrict__ ctr,
                                                   const u16* __restrict__ srcB,
                                                   const float* __restrict__ bias,
                                                   float* __restrict__ out) {
    const int wid = (blockIdx.x * 256 + threadIdx.x) >> 6;  // bucket = b*NN+nd
    const int lane = threadIdx.x & 63;
    const int half = lane >> 5, cl = lane & 31;
    int cnt = ctr[BM + wid];
    cnt = cnt > CAP ? CAP : cnt;
    const u16* lst = srcB + (size_t)wid * CAP;
    const u16* base = x_edge + (size_t)(wid / NN) * MM * CC + cl * 4;
    const float4 acc = bucket_mean_ps(base, lst, cnt, half);
    if (lane < 32) {
        const float w = cnt ? 1.0f / (float)cnt : 0.f;
        const float4 bv = *(const float4*)&bias[cl * 4];
        float4 o;
        o.x = acc.x * w + bv.x;
        o.y = acc.y * w + bv.y;
        o.z = acc.z * w + bv.z;
        o.w = acc.w * w + bv.w;
        *(float4*)&out[(size_t)wid * CC + cl * 4] = o;
    }
}

extern "C" void kernel_launch(void* const* d_in, const int* in_sizes, int n_in,
                              void* d_out, int out_size, void* d_ws, size_t ws_size,
                              hipStream_t stream) {
    const float* x = (const float*)d_in[0];
    const int* H = (const int*)d_in[1];
    const float* theta = (const float*)d_in[2];
    const float* bias = (const float*)d_in[3];
    float* out = (float*)d_out;

    // workspace (~31 MB): xt(bf16) | x_edge(bf16) | ctr | srcA32 | srcB32
    // ctr..srcB32 contiguous so ONE memset zeroes all (atomicOr needs zeroed slots).
    u16* xt = (u16*)d_ws;                              // 10.24 MB
    u16* x_edge = xt + (size_t)BB * NN * CC;           // 10.24 MB
    int* ctr = (int*)(x_edge + (size_t)BB * MM * CC);  // 320 KB
    u32* srcA = (u32*)(ctr + (BM + BN));               // 5.12 MB
    u32* srcB = srcA + (size_t)BM * (CAP / 2);         // 5.12 MB

    const size_t zero_bytes =
        (size_t)(BM + BN) * sizeof(int) + (size_t)(BM + BN) * (CAP / 2) * sizeof(u32);
    (void)hipMemsetAsync(ctr, 0, zero_bytes, stream);

    build_gemm_k<<<3750, 256, 0, stream>>>(H, ctr, srcA, srcB, x, theta, xt);
    phase1_pull<<<BM / 4, 256, 0, stream>>>(xt, ctr, (const u16*)srcA, x_edge);
    phase2_pull<<<BN / 4, 256, 0, stream>>>(x_edge, ctr, (const u16*)srcB, bias, out);
}